// Round 5
// baseline (554.544 us; speedup 1.0000x reference)
//
#include <hip/hip_runtime.h>

typedef unsigned short u16;
typedef unsigned int   u32;

#define SEQ 2048
#define EMB 2048
#define TD  6144

using bf16x8 = __attribute__((ext_vector_type(8))) __bf16;
using f32x4  = __attribute__((ext_vector_type(4))) float;

typedef __attribute__((address_space(1))) const void* gas_t;
typedef __attribute__((address_space(3))) void*       las_t;
#define GLOAD16(g, l) __builtin_amdgcn_global_load_lds((gas_t)(g), (las_t)(l), 16, 0, 0)

template <int N> struct IC { static constexpr int value = N; };

__device__ __forceinline__ u16 f2bf(float f) {
  u32 u = __float_as_uint(f);
  u += 0x7fffu + ((u >> 16) & 1u);   // round-to-nearest-even
  return (u16)(u >> 16);
}

// ---------------- cast x (fp32) -> xb (bf16) ----------------
__global__ __launch_bounds__(256) void cast_x_kern(const float* __restrict__ x,
                                                   u16* __restrict__ xb) {
  size_t i = ((size_t)blockIdx.x * 256 + threadIdx.x) * 4;
  float4 v = *(const float4*)(x + i);
  ushort4 u;
  u.x = f2bf(v.x); u.y = f2bf(v.y); u.z = f2bf(v.z); u.w = f2bf(v.w);
  *(ushort4*)(xb + i) = u;
}

// ---------------- cast + transpose W [EMB][TD] -> Wt [TD][EMB] bf16 ----------------
__global__ __launch_bounds__(256) void castT_W_kern(const float* __restrict__ W,
                                                    u16* __restrict__ Wt) {
  __shared__ float t[64][65];
  int c0 = blockIdx.x * 64, r0 = blockIdx.y * 64;
  int tid = threadIdx.x;
#pragma unroll
  for (int i = 0; i < 4; ++i) {
    int flat = i * 1024 + tid * 4;
    int r = flat >> 6, c = flat & 63;
    float4 v = *(const float4*)(W + (size_t)(r0 + r) * TD + c0 + c);
    t[r][c] = v.x; t[r][c + 1] = v.y; t[r][c + 2] = v.z; t[r][c + 3] = v.w;
  }
  __syncthreads();
#pragma unroll
  for (int i = 0; i < 4; ++i) {
    int flat = i * 1024 + tid * 4;
    int wr = flat >> 6, wc = flat & 63;
    ushort4 u;
    u.x = f2bf(t[wc + 0][wr]); u.y = f2bf(t[wc + 1][wr]);
    u.z = f2bf(t[wc + 2][wr]); u.w = f2bf(t[wc + 3][wr]);
    *(ushort4*)(Wt + (size_t)(c0 + wr) * EMB + r0 + wc) = u;
  }
}

// ---------------- transpose v: qkv v-slice [n][d] -> vT [d][n] per batch ----------------
__global__ __launch_bounds__(256) void transpose_v_kern(const u16* __restrict__ qkv,
                                                        u16* __restrict__ vT) {
  __shared__ u16 t[64][68];
  int b = blockIdx.z;
  int d0 = blockIdx.x * 64, n0 = blockIdx.y * 64;
  const u16* src = qkv + (size_t)b * SEQ * TD + 2 * SEQ;   // v at +4096 within row
  u16* dst = vT + (size_t)b * SEQ * SEQ;
  int tid = threadIdx.x;
#pragma unroll
  for (int i = 0; i < 4; ++i) {
    int flat = i * 1024 + tid * 4;
    int n = flat >> 6, d = flat & 63;
    *(ushort4*)&t[n][d] = *(const ushort4*)(src + (size_t)(n0 + n) * TD + d0 + d);
  }
  __syncthreads();
#pragma unroll
  for (int i = 0; i < 4; ++i) {
    int flat = i * 1024 + tid * 4;
    int d = flat >> 6, n = flat & 63;
    ushort4 u;
    u.x = t[n + 0][d]; u.y = t[n + 1][d]; u.z = t[n + 2][d]; u.w = t[n + 3][d];
    *(ushort4*)(dst + (size_t)(d0 + d) * SEQ + n0 + n) = u;
  }
}

// ------- 256x256 NT GEMM, intra-wave pipelined register loads (reads(p) feed MFMA(p+1)) ----
// Per phase: issue ds_reads for NEXT quad -> lgkmcnt(4) [drains LAST phase's reads] ->
// sched_barrier(0) -> 16 MFMA (regs loaded last phase) -> s_barrier.  One barrier/phase.
// Stage(t+1)=8 gloads at p0 -> vmcnt(0) at p2 -> p3 prefetches next tile quad0 + all B
// (12 reads, lgkmcnt(12) drains exactly p2's 4).  LDS: 4 distinct arrays, parity by
// unroll-2; register ping-pong aP/aQ by phase parity, bR[2] by tile parity (rule #20).
// MODE 0: qkv = xb @ Wt^T + bias (bf16 out).  grid 768
// MODE 1: att = scale * q @ k^T, causal 256-tile triangle. grid 144
// MODE 2: y = P @ vT^T, K = (qi+1)*256. grid 256
template <int MODE>
__global__ __launch_bounds__(512, 2) void gemm256(const u16* __restrict__ Ab,
                                                  const u16* __restrict__ Bb,
                                                  void* __restrict__ Cb,
                                                  const float* __restrict__ bias) {
  __shared__ u16 sA0[16384];   // 32KB: 256 rows x 64 cols bf16, row-XOR-swizzled
  __shared__ u16 sB0[16384];
  __shared__ u16 sA1[16384];
  __shared__ u16 sB1[16384];

  constexpr int lda = (MODE == 0) ? EMB : (MODE == 1) ? TD : 4096;
  constexpr int ldb = (MODE == 0) ? EMB : (MODE == 1) ? TD : SEQ;
  constexpr int NWG = (MODE == 0) ? 768 : (MODE == 1) ? 144 : 256;
  constexpr int CPX = NWG / 8;

  int bid = blockIdx.x;
  int wg = (bid & 7) * CPX + (bid >> 3);          // XCD-aware swizzle (NWG%8==0)

  const u16 *A, *Bt;
  int row0, col0, nk;
  size_t coff = 0;
  if constexpr (MODE == 0) {
    A = Ab; Bt = Bb;
    row0 = (wg / 24) * 256; col0 = (wg % 24) * 256; nk = EMB / 64;
  } else if constexpr (MODE == 1) {
    int b = wg / 36, tq = wg % 36;
    int qi = (int)((sqrtf(8.f * (float)tq + 1.f) - 1.f) * 0.5f);
    while ((qi + 1) * (qi + 2) / 2 <= tq) ++qi;
    while (qi * (qi + 1) / 2 > tq) --qi;
    int kj = tq - qi * (qi + 1) / 2;
    A = Ab + (size_t)b * SEQ * TD;       // q slice
    Bt = A + EMB;                        // k slice
    row0 = qi * 256; col0 = kj * 256; nk = EMB / 64;
    coff = (size_t)b * SEQ * SEQ;
  } else {
    int b = wg >> 6, qi = (wg >> 3) & 7, nj = wg & 7;
    A = Ab + (size_t)b * SEQ * 4096;     // P, row stride 4096 u16
    Bt = Bb + (size_t)b * SEQ * SEQ;     // vT
    row0 = qi * 256; col0 = nj * 256; nk = (qi + 1) * 4;   // even, >= 4
    coff = (size_t)b * SEQ * SEQ;
  }

  int tid = threadIdx.x;
  int wave = tid >> 6, lane = tid & 63;
  int wm = wave >> 2, wn = wave & 3;               // 2 x 4 wave grid, 128x64 out each
  int ln = lane & 15;

  auto stageB = [&](u16* SB, int i, int t) {
    int ob = i * 8192 + wave * 1024;
    int obl = ob + lane * 16;
    int row = obl >> 7, cb = obl & 127;
    int c = ((cb ^ ((row & 7) << 4)) >> 1) + t * 64;     // inverse swizzle on source
    GLOAD16(Bt + (size_t)(col0 + row) * ldb + c, (char*)SB + ob);
  };
  auto stageA = [&](u16* SA, int i, int t) {
    int ob = i * 4096 + ((wave < 4) ? wave * 1024 : 16384 + (wave - 4) * 1024);
    int obl = ob + lane * 16;
    int row = obl >> 7, cb = obl & 127;
    int c = ((cb ^ ((row & 7) << 4)) >> 1) + t * 64;
    GLOAD16(A + (size_t)(row0 + row) * lda + c, (char*)SA + ob);
  };
  auto ldfrag = [&](const u16* S, int rr, int ks) -> bf16x8 {
    int cb = ks * 64 + (lane >> 4) * 16;
    return *(const bf16x8*)((const char*)S + rr * 128 + (cb ^ ((rr & 7) << 4)));
  };

  f32x4 acc[8][4];
#pragma unroll
  for (int m = 0; m < 8; ++m)
#pragma unroll
    for (int n = 0; n < 4; ++n) acc[m][n] = (f32x4){0.f, 0.f, 0.f, 0.f};

  bf16x8 aP[2][2], aQ[2][2];     // A-quad ping-pong (phase parity)
  bf16x8 bR[2][4][2];            // B frags, tile parity

  auto LOADQ = [&](bf16x8 (&dst)[2][2], const u16* S, int q) {
#pragma unroll
    for (int m = 0; m < 2; ++m)
#pragma unroll
      for (int ks = 0; ks < 2; ++ks)
        dst[m][ks] = ldfrag(S, wm * 128 + q * 32 + m * 16 + ln, ks);
  };
  auto LOADB = [&](bf16x8 (&dst)[4][2], const u16* S) {
#pragma unroll
    for (int n = 0; n < 4; ++n)
#pragma unroll
      for (int ks = 0; ks < 2; ++ks)
        dst[n][ks] = ldfrag(S, wn * 64 + n * 16 + ln, ks);
  };
  auto MFMAQ = [&](auto QC, bf16x8 (&Af)[2][2], bf16x8 (&Bf)[4][2]) {
    constexpr int q = decltype(QC)::value;
    __builtin_amdgcn_s_setprio(1);
#pragma unroll
    for (int m = 0; m < 2; ++m)
#pragma unroll
      for (int n = 0; n < 4; ++n)
#pragma unroll
        for (int ks = 0; ks < 2; ++ks)
          acc[q * 2 + m][n] = __builtin_amdgcn_mfma_f32_16x16x32_bf16(
              Af[m][ks], Bf[n][ks], acc[q * 2 + m][n], 0, 0, 0);
    __builtin_amdgcn_s_setprio(0);
  };

  auto tile_step = [&](const u16* CA, const u16* CB, u16* NA, u16* NB, int t, auto TPC) {
    constexpr int tp = decltype(TPC)::value;
    bool pf = (t + 1 < nk);
    // ---- p0: consume aP(quad0), load aQ<-quad1; stage tile t+1 ----
    LOADQ(aQ, CA, 1);
    if (pf) {
      stageB(NB, 0, t + 1); stageB(NB, 1, t + 1); stageB(NB, 2, t + 1); stageB(NB, 3, t + 1);
      stageA(NA, 0, t + 1); stageA(NA, 1, t + 1); stageA(NA, 2, t + 1); stageA(NA, 3, t + 1);
    }
    asm volatile("s_waitcnt lgkmcnt(4)" ::: "memory");   // drains last phase's reads
    __builtin_amdgcn_sched_barrier(0);
    MFMAQ(IC<0>{}, aP, bR[tp]);
    __builtin_amdgcn_s_barrier();
    // ---- p1: consume aQ(quad1), load aP<-quad2 ----
    LOADQ(aP, CA, 2);
    asm volatile("s_waitcnt lgkmcnt(4)" ::: "memory");
    __builtin_amdgcn_sched_barrier(0);
    MFMAQ(IC<1>{}, aQ, bR[tp]);
    __builtin_amdgcn_s_barrier();
    // ---- p2: consume aP(quad2), load aQ<-quad3; drain stage ----
    LOADQ(aQ, CA, 3);
    asm volatile("s_waitcnt lgkmcnt(4)" ::: "memory");
    __builtin_amdgcn_sched_barrier(0);
    MFMAQ(IC<2>{}, aP, bR[tp]);
    if (pf) asm volatile("s_waitcnt vmcnt(0)" ::: "memory");  // stage(t+1) landed
    __builtin_amdgcn_s_barrier();
    // ---- p3: consume aQ(quad3), prefetch next tile quad0 + B ----
    if (pf) {
      LOADQ(aP, NA, 0);
      LOADB(bR[tp ^ 1], NB);
      asm volatile("s_waitcnt lgkmcnt(12)" ::: "memory");  // drains p2's 4, keeps 12
    } else {
      asm volatile("s_waitcnt lgkmcnt(0)" ::: "memory");
    }
    __builtin_amdgcn_sched_barrier(0);
    MFMAQ(IC<3>{}, aQ, bR[tp]);
    __builtin_amdgcn_s_barrier();
  };

  // prologue: stage tile 0 -> buf0; preload quad0 + B into registers
#pragma unroll
  for (int bi = 0; bi < 4; ++bi) stageB(sB0, bi, 0);
#pragma unroll
  for (int bi = 0; bi < 4; ++bi) stageA(sA0, bi, 0);
  asm volatile("s_waitcnt vmcnt(0)" ::: "memory");
  __builtin_amdgcn_s_barrier();
  LOADQ(aP, sA0, 0);
  LOADB(bR[0], sB0);

  for (int t2 = 0; t2 < nk; t2 += 2) {
    tile_step(sA0, sB0, sA1, sB1, t2,     IC<0>{});
    tile_step(sA1, sB1, sA0, sB0, t2 + 1, IC<1>{});
  }

  int l4 = (lane >> 4) << 2;
  int rb = row0 + wm * 128, cb0 = col0 + wn * 64;
  if constexpr (MODE == 0) {
    u16* C = (u16*)Cb;
#pragma unroll
    for (int n = 0; n < 4; ++n) {
      float bv = bias[cb0 + n * 16 + ln];
#pragma unroll
      for (int m = 0; m < 8; ++m)
#pragma unroll
        for (int r = 0; r < 4; ++r)
          C[(size_t)(rb + m * 16 + l4 + r) * TD + cb0 + n * 16 + ln] =
              f2bf(acc[m][n][r] + bv);
    }
  } else if constexpr (MODE == 1) {
    float* C = (float*)Cb + coff;
    const float scale = 0.022097086912079608f;   // 1/sqrt(2048)
#pragma unroll
    for (int m = 0; m < 8; ++m)
#pragma unroll
      for (int n = 0; n < 4; ++n)
#pragma unroll
        for (int r = 0; r < 4; ++r)
          C[(size_t)(rb + m * 16 + l4 + r) * SEQ + cb0 + n * 16 + ln] =
              acc[m][n][r] * scale;
  } else {
    float* C = (float*)Cb + coff;
#pragma unroll
    for (int m = 0; m < 8; ++m)
#pragma unroll
      for (int n = 0; n < 4; ++n)
#pragma unroll
        for (int r = 0; r < 4; ++r)
          C[(size_t)(rb + m * 16 + l4 + r) * SEQ + cb0 + n * 16 + ln] = acc[m][n][r];
  }
}

// ---------------- row softmax: att fp32 -> P bf16 (in place, stride 4096), denom ----------------
// extent is 256-granular to match the 256-tile GEMMs; masked entries produce exp->0.
__global__ __launch_bounds__(256) void softmax_kern(const float* __restrict__ att,
                                                    u16* __restrict__ P,
                                                    float* __restrict__ denom) {
  int row = blockIdx.x;          // b*SEQ + q
  int q = row & (SEQ - 1);
  const float* arow = att + (size_t)row * SEQ;
  u16* prow = P + (size_t)row * 4096;
  int jlen = ((q >> 8) + 1) << 8;          // 256-tile-aligned row extent
  int tid = threadIdx.x;
  int j0 = tid * 4, j1 = tid * 4 + 1024;
  float NI = -__builtin_inff();
  float4 a0 = make_float4(NI, NI, NI, NI), a1 = a0;
  if (j0 < jlen) a0 = *(const float4*)(arow + j0);
  if (j1 < jlen) a1 = *(const float4*)(arow + j1);
  if (j0 + 0 > q) a0.x = NI;
  if (j0 + 1 > q) a0.y = NI;
  if (j0 + 2 > q) a0.z = NI;
  if (j0 + 3 > q) a0.w = NI;
  if (j1 + 0 > q) a1.x = NI;
  if (j1 + 1 > q) a1.y = NI;
  if (j1 + 2 > q) a1.z = NI;
  if (j1 + 3 > q) a1.w = NI;
  float mx = fmaxf(fmaxf(fmaxf(a0.x, a0.y), fmaxf(a0.z, a0.w)),
                   fmaxf(fmaxf(a1.x, a1.y), fmaxf(a1.z, a1.w)));
#pragma unroll
  for (int off = 32; off; off >>= 1) mx = fmaxf(mx, __shfl_xor(mx, off, 64));
  __shared__ float red[8];
  int wv = tid >> 6;
  if ((tid & 63) == 0) red[wv] = mx;
  __syncthreads();
  mx = fmaxf(fmaxf(red[0], red[1]), fmaxf(red[2], red[3]));
  a0.x = expf(a0.x - mx); a0.y = expf(a0.y - mx);
  a0.z = expf(a0.z - mx); a0.w = expf(a0.w - mx);
  a1.x = expf(a1.x - mx); a1.y = expf(a1.y - mx);
  a1.z = expf(a1.z - mx); a1.w = expf(a1.w - mx);
  float s = (a0.x + a0.y + a0.z + a0.w) + (a1.x + a1.y + a1.z + a1.w);
#pragma unroll
  for (int off = 32; off; off >>= 1) s += __shfl_xor(s, off, 64);
  if ((tid & 63) == 0) red[4 + wv] = s;
  __syncthreads();                          // fences all arow reads before P writes
  s = red[4] + red[5] + red[6] + red[7];
  float inv = 1.0f / s;
  if (j0 < jlen) {
    ushort4 u;
    u.x = f2bf(a0.x * inv); u.y = f2bf(a0.y * inv);
    u.z = f2bf(a0.z * inv); u.w = f2bf(a0.w * inv);
    *(ushort4*)(prow + j0) = u;
  }
  if (j1 < jlen) {
    ushort4 u;
    u.x = f2bf(a1.x * inv); u.y = f2bf(a1.y * inv);
    u.z = f2bf(a1.z * inv); u.w = f2bf(a1.w * inv);
    *(ushort4*)(prow + j1) = u;
  }
  if (tid == 0) denom[row] = s;
}

extern "C" void kernel_launch(void* const* d_in, const int* in_sizes, int n_in,
                              void* d_out, int out_size, void* d_ws, size_t ws_size,
                              hipStream_t stream) {
  const float* x    = (const float*)d_in[0];
  const float* W    = (const float*)d_in[1];
  const float* bias = (const float*)d_in[2];

  // ws layout (201,326,592 B):
  //  [0,            100663296)  qkv bf16 [8192][6144]                 (persistent)
  //  [100663296,    134217728)  phase1: xb bf16     | phase2: vT bf16 [4][2048][2048]
  //  [134217728,    201326592)  phase1: Wt bf16 (first 25MB) | phase2: att fp32 / P bf16 in-place
  if (ws_size < 201326592u) return;

  char* w = (char*)d_ws;
  u16*   qkv = (u16*)w;
  u16*   xb  = (u16*)(w + 100663296);
  u16*   Wt  = (u16*)(w + 134217728);
  u16*   vT  = (u16*)(w + 100663296);
  float* att = (float*)(w + 134217728);
  u16*   P   = (u16*)(w + 134217728);

  float* y     = (float*)d_out;
  float* denom = y + (size_t)4 * SEQ * SEQ;

  cast_x_kern<<<16384, 256, 0, stream>>>(x, xb);
  castT_W_kern<<<dim3(96, 32), 256, 0, stream>>>(W, Wt);
  gemm256<0><<<768, 512, 0, stream>>>(xb, Wt, qkv, bias);
  transpose_v_kern<<<dim3(32, 32, 4), 256, 0, stream>>>(qkv, vT);
  gemm256<1><<<144, 512, 0, stream>>>(qkv, nullptr, att, nullptr);
  softmax_kern<<<8192, 256, 0, stream>>>(att, P, denom);
  gemm256<2><<<256, 512, 0, stream>>>(P, vT, y, nullptr);
}

// Round 6
// 341.363 us; speedup vs baseline: 1.6245x; 1.6245x over previous
//
#include <hip/hip_runtime.h>

typedef unsigned short u16;
typedef unsigned int   u32;

#define SEQ 2048
#define EMB 2048
#define TD  6144

using bf16x8 = __attribute__((ext_vector_type(8))) __bf16;
using f32x4  = __attribute__((ext_vector_type(4))) float;
using u16x8v = __attribute__((ext_vector_type(8))) u16;

typedef __attribute__((address_space(1))) const void* gas_t;
typedef __attribute__((address_space(3))) void*       las_t;
#define GLOAD16(g, l) __builtin_amdgcn_global_load_lds((gas_t)(g), (las_t)(l), 16, 0, 0)

__device__ __forceinline__ u16 f2bf(float f) {
  u32 u = __float_as_uint(f);
  u += 0x7fffu + ((u >> 16) & 1u);   // round-to-nearest-even
  return (u16)(u >> 16);
}

// ---------------- cast x (fp32) -> xb (bf16) ----------------
__global__ __launch_bounds__(256) void cast_x_kern(const float* __restrict__ x,
                                                   u16* __restrict__ xb) {
  size_t i = ((size_t)blockIdx.x * 256 + threadIdx.x) * 4;
  float4 v = *(const float4*)(x + i);
  ushort4 u;
  u.x = f2bf(v.x); u.y = f2bf(v.y); u.z = f2bf(v.z); u.w = f2bf(v.w);
  *(ushort4*)(xb + i) = u;
}

// ---------------- cast + transpose W [EMB][TD] -> Wt [TD][EMB] bf16 ----------------
__global__ __launch_bounds__(256) void castT_W_kern(const float* __restrict__ W,
                                                    u16* __restrict__ Wt) {
  __shared__ float t[64][65];
  int c0 = blockIdx.x * 64, r0 = blockIdx.y * 64;
  int tid = threadIdx.x;
#pragma unroll
  for (int i = 0; i < 4; ++i) {
    int flat = i * 1024 + tid * 4;
    int r = flat >> 6, c = flat & 63;
    float4 v = *(const float4*)(W + (size_t)(r0 + r) * TD + c0 + c);
    t[r][c] = v.x; t[r][c + 1] = v.y; t[r][c + 2] = v.z; t[r][c + 3] = v.w;
  }
  __syncthreads();
#pragma unroll
  for (int i = 0; i < 4; ++i) {
    int flat = i * 1024 + tid * 4;
    int wr = flat >> 6, wc = flat & 63;
    ushort4 u;
    u.x = f2bf(t[wc + 0][wr]); u.y = f2bf(t[wc + 1][wr]);
    u.z = f2bf(t[wc + 2][wr]); u.w = f2bf(t[wc + 3][wr]);
    *(ushort4*)(Wt + (size_t)(c0 + wr) * EMB + r0 + wc) = u;
  }
}

// ---------------- 256x256 8-phase NT GEMM, derived-waits pipeline (R3 core) ----------------
// C[i][j] = sum_k A[i][k] * Bt[j][k]
// Stage stream: 1 half-tile (2 bundles = 16KB) per phase. Tile X's bundles issue at
// phases (X-2).p1,p2,p3,(X-1).p0 -> at each tile boundary outstanding = {T.b6,b7, T+1.b0..b5}
// -> vmcnt(6) drains tile T with ~zero stall.
// MODE 0: [qk | vT] = xb @ Wt^T + bias. col<4096 -> qk[8192][4096] bf16;
//         col>=4096 -> vT[b][d][n] bf16 via in-LDS transpose (qkv v-slice never stored).
// MODE 1: att = scale * q @ k^T over qk (strides 4096), causal 256-tile triangle. grid 144
// MODE 2: y = P @ vT^T, K = (qi+1)*256. grid 256
template <int MODE>
__global__ __launch_bounds__(512, 2) void gemm256(const u16* __restrict__ Ab,
                                                  const u16* __restrict__ Bb,
                                                  void* __restrict__ Cb,
                                                  void* __restrict__ Cb2,
                                                  const float* __restrict__ bias) {
  // per buffer: A tile 256x64 bf16 (32KB) then B tile 256x64 (32KB); x2 buffers = 128KB
  __shared__ char lds[2][65536];

  constexpr int lda = (MODE == 0) ? EMB : 4096;
  constexpr int ldb = (MODE == 0) ? EMB : (MODE == 1) ? 4096 : SEQ;
  constexpr int NWG = (MODE == 0) ? 768 : (MODE == 1) ? 144 : 256;
  constexpr int CPX = NWG / 8;

  int bid = blockIdx.x;
  int wg = (bid & 7) * CPX + (bid >> 3);          // XCD-aware swizzle (NWG%8==0)

  const u16 *A, *Bt;
  int row0, col0, nk;
  size_t coff = 0;
  if constexpr (MODE == 0) {
    A = Ab; Bt = Bb;
    row0 = (wg / 24) * 256; col0 = (wg % 24) * 256; nk = EMB / 64;
  } else if constexpr (MODE == 1) {
    int b = wg / 36, tq = wg % 36;
    int qi = (int)((sqrtf(8.f * (float)tq + 1.f) - 1.f) * 0.5f);
    while ((qi + 1) * (qi + 2) / 2 <= tq) ++qi;
    while (qi * (qi + 1) / 2 > tq) --qi;
    int kj = tq - qi * (qi + 1) / 2;
    A = Ab + (size_t)b * SEQ * 4096;     // q slice (cols 0..2047 of qk)
    Bt = A + 2048;                       // k slice (cols 2048..4095)
    row0 = qi * 256; col0 = kj * 256; nk = EMB / 64;
    coff = (size_t)b * SEQ * SEQ;
  } else {
    int b = wg >> 6, qi = (wg >> 3) & 7, nj = wg & 7;
    A = Ab + (size_t)b * SEQ * 4096;     // P, row stride 4096 u16
    Bt = Bb + (size_t)b * SEQ * SEQ;     // vT
    row0 = qi * 256; col0 = nj * 256; nk = (qi + 1) * 4;
    coff = (size_t)b * SEQ * SEQ;
  }

  int tid = threadIdx.x;
  int wave = tid >> 6, lane = tid & 63;
  int wm = wave >> 2, wn = wave & 3;               // 2 x 4 wave grid, 128x64 out each

  // Stage-bundle LDS byte bases (uniform per wave). One bundle = 8KB block-wide.
  // b0..b3: B tile (reads finish in phase 0 - B is register-cached for the tile).
  // b4: A rows {0-31,128-159} (phase-0 reads)  b5: {32-63,160-191} (phase 1)
  // b6: {64-95,192-223} (phase 2)              b7: {96-127,224-255} (phase 3)
  int sbase[8];
#pragma unroll
  for (int i = 0; i < 4; ++i) sbase[i] = 32768 + i * 8192 + wave * 1024;
#pragma unroll
  for (int i = 0; i < 4; ++i)
    sbase[4 + i] = i * 4096 + ((wave < 4) ? wave * 1024 : 16384 + (wave - 4) * 1024);

  // linear LDS dest + inverse-swizzled global source (rule #21); swizzle: byte ^= (row&7)<<4
  auto stageb = [&](int bi, int t, int buf) {
    int ob = sbase[bi];
    int obl = ob + lane * 16;
    int row = (obl & 32767) >> 7;
    int cb = obl & 127;
    int c = ((cb ^ ((row & 7) << 4)) >> 1) + t * 64;
    const u16* src = (ob < 32768) ? (A + (size_t)(row0 + row) * lda + c)
                                  : (Bt + (size_t)(col0 + row) * ldb + c);
    GLOAD16(src, (char*)&lds[buf][0] + ob);
  };

  auto ldA = [&](int buf, int rr, int ks) -> bf16x8 {
    int cb = ks * 64 + (lane >> 4) * 16;
    return *(const bf16x8*)&lds[buf][rr * 128 + (cb ^ ((rr & 7) << 4))];
  };
  auto ldB = [&](int buf, int rr, int ks) -> bf16x8 {
    int cb = ks * 64 + (lane >> 4) * 16;
    return *(const bf16x8*)&lds[buf][32768 + rr * 128 + (cb ^ ((rr & 7) << 4))];
  };

  f32x4 acc[8][4];
#pragma unroll
  for (int m = 0; m < 8; ++m)
#pragma unroll
    for (int n = 0; n < 4; ++n) acc[m][n] = (f32x4){0.f, 0.f, 0.f, 0.f};

  // prologue: tile0 fully, tile1 b0..b5; vmcnt(6) -> tile0 landed
#pragma unroll
  for (int bi = 0; bi < 8; ++bi) stageb(bi, 0, 0);
#pragma unroll
  for (int bi = 0; bi < 6; ++bi) stageb(bi, 1, 1);
  asm volatile("s_waitcnt vmcnt(6)" ::: "memory");
  __builtin_amdgcn_s_barrier();

  bf16x8 bfg[4][2];
  for (int t = 0; t < nk; ++t) {
    int cur = t & 1, nxt = cur ^ 1;
#pragma unroll
    for (int p = 0; p < 4; ++p) {
      // --- ds-load register subtile (phase p consumes A-quadrant p; B all at p0) ---
      bf16x8 afg[2][2];
      if (p == 0) {
#pragma unroll
        for (int n = 0; n < 4; ++n)
#pragma unroll
          for (int ks = 0; ks < 2; ++ks)
            bfg[n][ks] = ldB(cur, wn * 64 + n * 16 + (lane & 15), ks);
      }
#pragma unroll
      for (int m = 0; m < 2; ++m)
#pragma unroll
        for (int ks = 0; ks < 2; ++ks)
          afg[m][ks] = ldA(cur, wm * 128 + (p * 2 + m) * 16 + (lane & 15), ks);
      // --- stage exactly one half-tile (2 bundles) per phase ---
      if (p == 0) {
        if (t + 1 < nk) { stageb(6, t + 1, nxt); stageb(7, t + 1, nxt); }
        asm volatile("s_waitcnt lgkmcnt(8)" ::: "memory");   // 12 ds_reads this phase
      } else if (t + 2 < nk) {
        stageb(2 * (p - 1), t + 2, cur);
        stageb(2 * (p - 1) + 1, t + 2, cur);
      }
      __builtin_amdgcn_s_barrier();
      asm volatile("s_waitcnt lgkmcnt(0)" ::: "memory");
      __builtin_amdgcn_s_setprio(1);
#pragma unroll
      for (int m = 0; m < 2; ++m)
#pragma unroll
        for (int n = 0; n < 4; ++n)
#pragma unroll
          for (int ks = 0; ks < 2; ++ks)
            acc[p * 2 + m][n] = __builtin_amdgcn_mfma_f32_16x16x32_bf16(
                afg[m][ks], bfg[n][ks], acc[p * 2 + m][n], 0, 0, 0);
      __builtin_amdgcn_s_setprio(0);
      if (p == 3) {            // tile boundary: derived wait, never 0 in steady state
        if (t + 2 < nk)       asm volatile("s_waitcnt vmcnt(6)" ::: "memory");
        else if (t + 1 < nk)  asm volatile("s_waitcnt vmcnt(0)" ::: "memory");
      }
      __builtin_amdgcn_s_barrier();
    }
  }

  int ln = lane & 15;
  int l4 = (lane >> 4) << 2;
  int rb = row0 + wm * 128, cb0 = col0 + wn * 64;
  if constexpr (MODE == 0) {
    if (col0 < 4096) {
      // q/k tile -> qk buffer [8192][4096]
      u16* C = (u16*)Cb;
#pragma unroll
      for (int n = 0; n < 4; ++n) {
        float bv = bias[cb0 + n * 16 + ln];
#pragma unroll
        for (int m = 0; m < 8; ++m)
#pragma unroll
          for (int r = 0; r < 4; ++r)
            C[(size_t)(rb + m * 16 + l4 + r) * 4096 + cb0 + n * 16 + ln] =
                f2bf(acc[m][n][r] + bv);
      }
    } else {
      // v tile -> vT[b][d][n] via in-LDS transpose (two 128-d passes)
      u16* vTb = (u16*)Cb2 + (size_t)(row0 >> 11) * SEQ * SEQ;
      int nbase = row0 & 2047;
      u16 (*T)[264] = (u16(*)[264])(&lds[0][0]);     // 128 x 264 u16 = 66KB of 128KB
      int half = wn >> 1;                             // which d-half this wave holds
      int dloc0 = (wn & 1) * 64;
#pragma unroll
      for (int hh = 0; hh < 2; ++hh) {
        if (half == hh) {
#pragma unroll
          for (int n = 0; n < 4; ++n) {
            float bv = bias[cb0 + n * 16 + ln];
            int dl = dloc0 + n * 16 + ln;
#pragma unroll
            for (int m = 0; m < 8; ++m) {
              int nn = wm * 128 + m * 16 + l4;
#pragma unroll
              for (int r = 0; r < 4; ++r)
                T[dl][nn + r] = f2bf(acc[m][n][r] + bv);
            }
          }
        }
        __syncthreads();
        int dl = tid >> 5, nn = (tid & 31) * 8;
#pragma unroll
        for (int it = 0; it < 8; ++it) {
          int loc = it * 16 + dl;
          *(u16x8v*)&vTb[(size_t)(col0 - 4096 + hh * 128 + loc) * SEQ + nbase + nn] =
              *(const u16x8v*)&T[loc][nn];
        }
        __syncthreads();
      }
    }
  } else if constexpr (MODE == 1) {
    float* C = (float*)Cb + coff;
    const float scale = 0.022097086912079608f;   // 1/sqrt(2048)
#pragma unroll
    for (int m = 0; m < 8; ++m)
#pragma unroll
      for (int n = 0; n < 4; ++n)
#pragma unroll
        for (int r = 0; r < 4; ++r)
          C[(size_t)(rb + m * 16 + l4 + r) * SEQ + cb0 + n * 16 + ln] =
              acc[m][n][r] * scale;
  } else {
    float* C = (float*)Cb + coff;
#pragma unroll
    for (int m = 0; m < 8; ++m)
#pragma unroll
      for (int n = 0; n < 4; ++n)
#pragma unroll
        for (int r = 0; r < 4; ++r)
          C[(size_t)(rb + m * 16 + l4 + r) * SEQ + cb0 + n * 16 + ln] = acc[m][n][r];
  }
}

// ---------------- row softmax: att fp32 -> P bf16 (in place, stride 4096), denom ----------------
// extent is 256-granular to match the 256-tile GEMMs; masked entries produce exp->0.
__global__ __launch_bounds__(256) void softmax_kern(const float* __restrict__ att,
                                                    u16* __restrict__ P,
                                                    float* __restrict__ denom) {
  int row = blockIdx.x;          // b*SEQ + q
  int q = row & (SEQ - 1);
  const float* arow = att + (size_t)row * SEQ;
  u16* prow = P + (size_t)row * 4096;
  int jlen = ((q >> 8) + 1) << 8;          // 256-tile-aligned row extent
  int tid = threadIdx.x;
  int j0 = tid * 4, j1 = tid * 4 + 1024;
  float NI = -__builtin_inff();
  float4 a0 = make_float4(NI, NI, NI, NI), a1 = a0;
  if (j0 < jlen) a0 = *(const float4*)(arow + j0);
  if (j1 < jlen) a1 = *(const float4*)(arow + j1);
  if (j0 + 0 > q) a0.x = NI;
  if (j0 + 1 > q) a0.y = NI;
  if (j0 + 2 > q) a0.z = NI;
  if (j0 + 3 > q) a0.w = NI;
  if (j1 + 0 > q) a1.x = NI;
  if (j1 + 1 > q) a1.y = NI;
  if (j1 + 2 > q) a1.z = NI;
  if (j1 + 3 > q) a1.w = NI;
  float mx = fmaxf(fmaxf(fmaxf(a0.x, a0.y), fmaxf(a0.z, a0.w)),
                   fmaxf(fmaxf(a1.x, a1.y), fmaxf(a1.z, a1.w)));
#pragma unroll
  for (int off = 32; off; off >>= 1) mx = fmaxf(mx, __shfl_xor(mx, off, 64));
  __shared__ float red[8];
  int wv = tid >> 6;
  if ((tid & 63) == 0) red[wv] = mx;
  __syncthreads();
  mx = fmaxf(fmaxf(red[0], red[1]), fmaxf(red[2], red[3]));
  a0.x = expf(a0.x - mx); a0.y = expf(a0.y - mx);
  a0.z = expf(a0.z - mx); a0.w = expf(a0.w - mx);
  a1.x = expf(a1.x - mx); a1.y = expf(a1.y - mx);
  a1.z = expf(a1.z - mx); a1.w = expf(a1.w - mx);
  float s = (a0.x + a0.y + a0.z + a0.w) + (a1.x + a1.y + a1.z + a1.w);
#pragma unroll
  for (int off = 32; off; off >>= 1) s += __shfl_xor(s, off, 64);
  if ((tid & 63) == 0) red[4 + wv] = s;
  __syncthreads();                          // fences all arow reads before P writes
  s = red[4] + red[5] + red[6] + red[7];
  float inv = 1.0f / s;
  if (j0 < jlen) {
    ushort4 u;
    u.x = f2bf(a0.x * inv); u.y = f2bf(a0.y * inv);
    u.z = f2bf(a0.z * inv); u.w = f2bf(a0.w * inv);
    *(ushort4*)(prow + j0) = u;
  }
  if (j1 < jlen) {
    ushort4 u;
    u.x = f2bf(a1.x * inv); u.y = f2bf(a1.y * inv);
    u.z = f2bf(a1.z * inv); u.w = f2bf(a1.w * inv);
    *(ushort4*)(prow + j1) = u;
  }
  if (tid == 0) denom[row] = s;
}

extern "C" void kernel_launch(void* const* d_in, const int* in_sizes, int n_in,
                              void* d_out, int out_size, void* d_ws, size_t ws_size,
                              hipStream_t stream) {
  const float* x    = (const float*)d_in[0];
  const float* W    = (const float*)d_in[1];
  const float* bias = (const float*)d_in[2];

  // ws layout (201,326,592 B):
  //  [0,         67108864)  qk bf16 [8192][4096] (q cols 0..2047, k cols 2048..4095)
  //  [67108864, 100663296)  vT bf16 [4][2048][2048]   (written by gemm<0> epilogue)
  //  [100663296,134217728)  xb bf16 [8192][2048]      (dead after gemm<0>)
  //  [134217728,201326592)  phase1: Wt bf16 (first 25MB, dead after gemm<0>)
  //                         phase2: att fp32 / P bf16 in-place (row stride 4096 u16)
  if (ws_size < 201326592u) return;

  char* w = (char*)d_ws;
  u16*   qk  = (u16*)w;
  u16*   vT  = (u16*)(w + 67108864);
  u16*   xb  = (u16*)(w + 100663296);
  u16*   Wt  = (u16*)(w + 134217728);
  float* att = (float*)(w + 134217728);
  u16*   P   = (u16*)(w + 134217728);

  float* y     = (float*)d_out;
  float* denom = y + (size_t)4 * SEQ * SEQ;

  cast_x_kern<<<16384, 256, 0, stream>>>(x, xb);
  castT_W_kern<<<dim3(96, 32), 256, 0, stream>>>(W, Wt);
  gemm256<0><<<768, 512, 0, stream>>>(xb, Wt, qk, vT, bias);
  gemm256<1><<<144, 512, 0, stream>>>(qk, nullptr, att, nullptr, nullptr);
  softmax_kern<<<8192, 256, 0, stream>>>(att, P, denom);
  gemm256<2><<<256, 512, 0, stream>>>(P, vT, y, nullptr, nullptr);
}

// Round 7
// 334.362 us; speedup vs baseline: 1.6585x; 1.0209x over previous
//
#include <hip/hip_runtime.h>

typedef unsigned short u16;
typedef unsigned int   u32;

#define SEQ 2048
#define EMB 2048
#define TD  6144

using bf16x8 = __attribute__((ext_vector_type(8))) __bf16;
using f32x4  = __attribute__((ext_vector_type(4))) float;
using u16x8v = __attribute__((ext_vector_type(8))) u16;

typedef __attribute__((address_space(1))) const void* gas_t;
typedef __attribute__((address_space(3))) void*       las_t;
#define GLOAD16(g, l) __builtin_amdgcn_global_load_lds((gas_t)(g), (las_t)(l), 16, 0, 0)

__device__ __forceinline__ u16 f2bf(float f) {
  u32 u = __float_as_uint(f);
  u += 0x7fffu + ((u >> 16) & 1u);   // round-to-nearest-even
  return (u16)(u >> 16);
}

// ---------------- cast x (fp32) -> xb (bf16) ----------------
__global__ __launch_bounds__(256) void cast_x_kern(const float* __restrict__ x,
                                                   u16* __restrict__ xb) {
  size_t i = ((size_t)blockIdx.x * 256 + threadIdx.x) * 4;
  float4 v = *(const float4*)(x + i);
  ushort4 u;
  u.x = f2bf(v.x); u.y = f2bf(v.y); u.z = f2bf(v.z); u.w = f2bf(v.w);
  *(ushort4*)(xb + i) = u;
}

// ---------------- cast + transpose W [EMB][TD] -> Wt [TD][EMB] bf16 ----------------
__global__ __launch_bounds__(256) void castT_W_kern(const float* __restrict__ W,
                                                    u16* __restrict__ Wt) {
  __shared__ float t[64][65];
  int c0 = blockIdx.x * 64, r0 = blockIdx.y * 64;
  int tid = threadIdx.x;
#pragma unroll
  for (int i = 0; i < 4; ++i) {
    int flat = i * 1024 + tid * 4;
    int r = flat >> 6, c = flat & 63;
    float4 v = *(const float4*)(W + (size_t)(r0 + r) * TD + c0 + c);
    t[r][c] = v.x; t[r][c + 1] = v.y; t[r][c + 2] = v.z; t[r][c + 3] = v.w;
  }
  __syncthreads();
#pragma unroll
  for (int i = 0; i < 4; ++i) {
    int flat = i * 1024 + tid * 4;
    int wr = flat >> 6, wc = flat & 63;
    ushort4 u;
    u.x = f2bf(t[wc + 0][wr]); u.y = f2bf(t[wc + 1][wr]);
    u.z = f2bf(t[wc + 2][wr]); u.w = f2bf(t[wc + 3][wr]);
    *(ushort4*)(Wt + (size_t)(c0 + wr) * EMB + r0 + wc) = u;
  }
}

// ---------------- 256x256 8-phase NT GEMM, derived waits + minimal barriers ----------------
// C[i][j] = sum_k A[i][k] * Bt[j][k]
// R7 change vs R6: barriers 8->3 per K-tile (p0-end, p2-end, p3-end) and NO lgkm asm --
// plain ds-reads let the compiler emit exact counted lgkm waits and pipeline reads under
// MFMA across the barrier-free stretches. Hazard audit: p1/p2 stages (B halves) covered by
// p0-end barrier; p3 stage (A q0,q1) covered by p2-end; next-tile p0 stage (nxt q2,q3)
// covered by p3-end. vmcnt(6) at p3 drains exactly tile t+1 (14 outstanding -> 6).
// MODE 0: [qk | vT] = xb @ Wt^T + bias. col<4096 -> qk[8192][4096] bf16;
//         col>=4096 -> vT[b][d][n] bf16 via in-LDS transpose.
// MODE 1: att = scale * q @ k^T over qk (strides 4096), causal 256-tile triangle. grid 144
// MODE 2: y = P @ vT^T, K = (qi+1)*256. grid 256
template <int MODE>
__global__ __launch_bounds__(512, 2) void gemm256(const u16* __restrict__ Ab,
                                                  const u16* __restrict__ Bb,
                                                  void* __restrict__ Cb,
                                                  void* __restrict__ Cb2,
                                                  const float* __restrict__ bias) {
  // per buffer: A tile 256x64 bf16 (32KB) then B tile 256x64 (32KB); x2 buffers = 128KB
  __shared__ char lds[2][65536];

  constexpr int lda = (MODE == 0) ? EMB : 4096;
  constexpr int ldb = (MODE == 0) ? EMB : (MODE == 1) ? 4096 : SEQ;
  constexpr int NWG = (MODE == 0) ? 768 : (MODE == 1) ? 144 : 256;
  constexpr int CPX = NWG / 8;

  int bid = blockIdx.x;
  int wg = (bid & 7) * CPX + (bid >> 3);          // XCD-aware swizzle (NWG%8==0)

  const u16 *A, *Bt;
  int row0, col0, nk;
  size_t coff = 0;
  if constexpr (MODE == 0) {
    A = Ab; Bt = Bb;
    row0 = (wg / 24) * 256; col0 = (wg % 24) * 256; nk = EMB / 64;
  } else if constexpr (MODE == 1) {
    int b = wg / 36, tq = wg % 36;
    int qi = (int)((sqrtf(8.f * (float)tq + 1.f) - 1.f) * 0.5f);
    while ((qi + 1) * (qi + 2) / 2 <= tq) ++qi;
    while (qi * (qi + 1) / 2 > tq) --qi;
    int kj = tq - qi * (qi + 1) / 2;
    A = Ab + (size_t)b * SEQ * 4096;     // q slice (cols 0..2047 of qk)
    Bt = A + 2048;                       // k slice (cols 2048..4095)
    row0 = qi * 256; col0 = kj * 256; nk = EMB / 64;
    coff = (size_t)b * SEQ * SEQ;
  } else {
    int b = wg >> 6, qi = (wg >> 3) & 7, nj = wg & 7;
    A = Ab + (size_t)b * SEQ * 4096;     // P, row stride 4096 u16
    Bt = Bb + (size_t)b * SEQ * SEQ;     // vT
    row0 = qi * 256; col0 = nj * 256; nk = (qi + 1) * 4;
    coff = (size_t)b * SEQ * SEQ;
  }

  int tid = threadIdx.x;
  int wave = tid >> 6, lane = tid & 63;
  int wm = wave >> 2, wn = wave & 3;               // 2 x 4 wave grid, 128x64 out each

  // Stage-bundle LDS byte bases (uniform per wave). One bundle = 8KB block-wide.
  // b0..b3: B tile.  b4..b7: A quadrants {rows q*32..q*32+31} u {128+q*32..+31}.
  int sbase[8];
#pragma unroll
  for (int i = 0; i < 4; ++i) sbase[i] = 32768 + i * 8192 + wave * 1024;
#pragma unroll
  for (int i = 0; i < 4; ++i)
    sbase[4 + i] = i * 4096 + ((wave < 4) ? wave * 1024 : 16384 + (wave - 4) * 1024);

  // linear LDS dest + inverse-swizzled global source (rule #21); swizzle: byte ^= (row&7)<<4
  auto stageb = [&](int bi, int t, int buf) {
    int ob = sbase[bi];
    int obl = ob + lane * 16;
    int row = (obl & 32767) >> 7;
    int cb = obl & 127;
    int c = ((cb ^ ((row & 7) << 4)) >> 1) + t * 64;
    const u16* src = (ob < 32768) ? (A + (size_t)(row0 + row) * lda + c)
                                  : (Bt + (size_t)(col0 + row) * ldb + c);
    GLOAD16(src, (char*)&lds[buf][0] + ob);
  };

  auto ldA = [&](int buf, int rr, int ks) -> bf16x8 {
    int cb = ks * 64 + (lane >> 4) * 16;
    return *(const bf16x8*)&lds[buf][rr * 128 + (cb ^ ((rr & 7) << 4))];
  };
  auto ldB = [&](int buf, int rr, int ks) -> bf16x8 {
    int cb = ks * 64 + (lane >> 4) * 16;
    return *(const bf16x8*)&lds[buf][32768 + rr * 128 + (cb ^ ((rr & 7) << 4))];
  };

  f32x4 acc[8][4];
#pragma unroll
  for (int m = 0; m < 8; ++m)
#pragma unroll
    for (int n = 0; n < 4; ++n) acc[m][n] = (f32x4){0.f, 0.f, 0.f, 0.f};

  // prologue: tile0 fully, tile1 b0..b5; vmcnt(6) -> tile0 landed
#pragma unroll
  for (int bi = 0; bi < 8; ++bi) stageb(bi, 0, 0);
#pragma unroll
  for (int bi = 0; bi < 6; ++bi) stageb(bi, 1, 1);
  asm volatile("s_waitcnt vmcnt(6)" ::: "memory");
  __builtin_amdgcn_s_barrier();

  bf16x8 bfg[4][2];
  for (int t = 0; t < nk; ++t) {
    int cur = t & 1, nxt = cur ^ 1;
    bool pf1 = (t + 1 < nk), pf2 = (t + 2 < nk);
    bf16x8 afg[2][2];

    // ---- p0: read B(8) + A-quad0(4); stage t+1.b6,b7 -> nxt; MFMA q0; BARRIER ----
#pragma unroll
    for (int n = 0; n < 4; ++n)
#pragma unroll
      for (int ks = 0; ks < 2; ++ks)
        bfg[n][ks] = ldB(cur, wn * 64 + n * 16 + (lane & 15), ks);
#pragma unroll
    for (int m = 0; m < 2; ++m)
#pragma unroll
      for (int ks = 0; ks < 2; ++ks)
        afg[m][ks] = ldA(cur, wm * 128 + m * 16 + (lane & 15), ks);
    if (pf1) { stageb(6, t + 1, nxt); stageb(7, t + 1, nxt); }
    __builtin_amdgcn_s_setprio(1);
#pragma unroll
    for (int m = 0; m < 2; ++m)
#pragma unroll
      for (int n = 0; n < 4; ++n)
#pragma unroll
        for (int ks = 0; ks < 2; ++ks)
          acc[m][n] = __builtin_amdgcn_mfma_f32_16x16x32_bf16(
              afg[m][ks], bfg[n][ks], acc[m][n], 0, 0, 0);
    __builtin_amdgcn_s_setprio(0);
    __builtin_amdgcn_s_barrier();

    // ---- p1: read A-quad1; stage t+2.b0,b1 -> cur; MFMA q1 (no barrier) ----
#pragma unroll
    for (int m = 0; m < 2; ++m)
#pragma unroll
      for (int ks = 0; ks < 2; ++ks)
        afg[m][ks] = ldA(cur, wm * 128 + (2 + m) * 16 + (lane & 15), ks);
    if (pf2) { stageb(0, t + 2, cur); stageb(1, t + 2, cur); }
    __builtin_amdgcn_s_setprio(1);
#pragma unroll
    for (int m = 0; m < 2; ++m)
#pragma unroll
      for (int n = 0; n < 4; ++n)
#pragma unroll
        for (int ks = 0; ks < 2; ++ks)
          acc[2 + m][n] = __builtin_amdgcn_mfma_f32_16x16x32_bf16(
              afg[m][ks], bfg[n][ks], acc[2 + m][n], 0, 0, 0);
    __builtin_amdgcn_s_setprio(0);

    // ---- p2: read A-quad2; stage t+2.b2,b3 -> cur; MFMA q2; BARRIER ----
#pragma unroll
    for (int m = 0; m < 2; ++m)
#pragma unroll
      for (int ks = 0; ks < 2; ++ks)
        afg[m][ks] = ldA(cur, wm * 128 + (4 + m) * 16 + (lane & 15), ks);
    if (pf2) { stageb(2, t + 2, cur); stageb(3, t + 2, cur); }
    __builtin_amdgcn_s_setprio(1);
#pragma unroll
    for (int m = 0; m < 2; ++m)
#pragma unroll
      for (int n = 0; n < 4; ++n)
#pragma unroll
        for (int ks = 0; ks < 2; ++ks)
          acc[4 + m][n] = __builtin_amdgcn_mfma_f32_16x16x32_bf16(
              afg[m][ks], bfg[n][ks], acc[4 + m][n], 0, 0, 0);
    __builtin_amdgcn_s_setprio(0);
    __builtin_amdgcn_s_barrier();

    // ---- p3: read A-quad3; stage t+2.b4,b5 -> cur; MFMA q3; vmcnt; BARRIER ----
#pragma unroll
    for (int m = 0; m < 2; ++m)
#pragma unroll
      for (int ks = 0; ks < 2; ++ks)
        afg[m][ks] = ldA(cur, wm * 128 + (6 + m) * 16 + (lane & 15), ks);
    if (pf2) { stageb(4, t + 2, cur); stageb(5, t + 2, cur); }
    __builtin_amdgcn_s_setprio(1);
#pragma unroll
    for (int m = 0; m < 2; ++m)
#pragma unroll
      for (int n = 0; n < 4; ++n)
#pragma unroll
        for (int ks = 0; ks < 2; ++ks)
          acc[6 + m][n] = __builtin_amdgcn_mfma_f32_16x16x32_bf16(
              afg[m][ks], bfg[n][ks], acc[6 + m][n], 0, 0, 0);
    __builtin_amdgcn_s_setprio(0);
    if (pf2)      asm volatile("s_waitcnt vmcnt(6)" ::: "memory");
    else if (pf1) asm volatile("s_waitcnt vmcnt(0)" ::: "memory");
    __builtin_amdgcn_s_barrier();
  }

  int ln = lane & 15;
  int l4 = (lane >> 4) << 2;
  int rb = row0 + wm * 128, cb0 = col0 + wn * 64;
  if constexpr (MODE == 0) {
    if (col0 < 4096) {
      // q/k tile -> qk buffer [8192][4096]
      u16* C = (u16*)Cb;
#pragma unroll
      for (int n = 0; n < 4; ++n) {
        float bv = bias[cb0 + n * 16 + ln];
#pragma unroll
        for (int m = 0; m < 8; ++m)
#pragma unroll
          for (int r = 0; r < 4; ++r)
            C[(size_t)(rb + m * 16 + l4 + r) * 4096 + cb0 + n * 16 + ln] =
                f2bf(acc[m][n][r] + bv);
      }
    } else {
      // v tile -> vT[b][d][n] via in-LDS transpose (two 128-d passes)
      u16* vTb = (u16*)Cb2 + (size_t)(row0 >> 11) * SEQ * SEQ;
      int nbase = row0 & 2047;
      u16 (*T)[264] = (u16(*)[264])(&lds[0][0]);     // 128 x 264 u16 = 66KB of 128KB
      int half = wn >> 1;                             // which d-half this wave holds
      int dloc0 = (wn & 1) * 64;
#pragma unroll
      for (int hh = 0; hh < 2; ++hh) {
        if (half == hh) {
#pragma unroll
          for (int n = 0; n < 4; ++n) {
            float bv = bias[cb0 + n * 16 + ln];
            int dl = dloc0 + n * 16 + ln;
#pragma unroll
            for (int m = 0; m < 8; ++m) {
              int nn = wm * 128 + m * 16 + l4;
#pragma unroll
              for (int r = 0; r < 4; ++r)
                T[dl][nn + r] = f2bf(acc[m][n][r] + bv);
            }
          }
        }
        __syncthreads();
        int dl = tid >> 5, nn = (tid & 31) * 8;
#pragma unroll
        for (int it = 0; it < 8; ++it) {
          int loc = it * 16 + dl;
          *(u16x8v*)&vTb[(size_t)(col0 - 4096 + hh * 128 + loc) * SEQ + nbase + nn] =
              *(const u16x8v*)&T[loc][nn];
        }
        __syncthreads();
      }
    }
  } else if constexpr (MODE == 1) {
    float* C = (float*)Cb + coff;
    const float scale = 0.022097086912079608f;   // 1/sqrt(2048)
#pragma unroll
    for (int m = 0; m < 8; ++m)
#pragma unroll
      for (int n = 0; n < 4; ++n)
#pragma unroll
        for (int r = 0; r < 4; ++r)
          C[(size_t)(rb + m * 16 + l4 + r) * SEQ + cb0 + n * 16 + ln] =
              acc[m][n][r] * scale;
  } else {
    float* C = (float*)Cb + coff;
#pragma unroll
    for (int m = 0; m < 8; ++m)
#pragma unroll
      for (int n = 0; n < 4; ++n)
#pragma unroll
        for (int r = 0; r < 4; ++r)
          C[(size_t)(rb + m * 16 + l4 + r) * SEQ + cb0 + n * 16 + ln] = acc[m][n][r];
  }
}

// ---------------- row softmax: att fp32 -> P bf16 (in place, stride 4096), denom ----------------
// extent is 256-granular to match the 256-tile GEMMs; masked entries produce exp->0.
__global__ __launch_bounds__(256) void softmax_kern(const float* __restrict__ att,
                                                    u16* __restrict__ P,
                                                    float* __restrict__ denom) {
  int row = blockIdx.x;          // b*SEQ + q
  int q = row & (SEQ - 1);
  const float* arow = att + (size_t)row * SEQ;
  u16* prow = P + (size_t)row * 4096;
  int jlen = ((q >> 8) + 1) << 8;          // 256-tile-aligned row extent
  int tid = threadIdx.x;
  int j0 = tid * 4, j1 = tid * 4 + 1024;
  float NI = -__builtin_inff();
  float4 a0 = make_float4(NI, NI, NI, NI), a1 = a0;
  if (j0 < jlen) a0 = *(const float4*)(arow + j0);
  if (j1 < jlen) a1 = *(const float4*)(arow + j1);
  if (j0 + 0 > q) a0.x = NI;
  if (j0 + 1 > q) a0.y = NI;
  if (j0 + 2 > q) a0.z = NI;
  if (j0 + 3 > q) a0.w = NI;
  if (j1 + 0 > q) a1.x = NI;
  if (j1 + 1 > q) a1.y = NI;
  if (j1 + 2 > q) a1.z = NI;
  if (j1 + 3 > q) a1.w = NI;
  float mx = fmaxf(fmaxf(fmaxf(a0.x, a0.y), fmaxf(a0.z, a0.w)),
                   fmaxf(fmaxf(a1.x, a1.y), fmaxf(a1.z, a1.w)));
#pragma unroll
  for (int off = 32; off; off >>= 1) mx = fmaxf(mx, __shfl_xor(mx, off, 64));
  __shared__ float red[8];
  int wv = tid >> 6;
  if ((tid & 63) == 0) red[wv] = mx;
  __syncthreads();
  mx = fmaxf(fmaxf(red[0], red[1]), fmaxf(red[2], red[3]));
  a0.x = expf(a0.x - mx); a0.y = expf(a0.y - mx);
  a0.z = expf(a0.z - mx); a0.w = expf(a0.w - mx);
  a1.x = expf(a1.x - mx); a1.y = expf(a1.y - mx);
  a1.z = expf(a1.z - mx); a1.w = expf(a1.w - mx);
  float s = (a0.x + a0.y + a0.z + a0.w) + (a1.x + a1.y + a1.z + a1.w);
#pragma unroll
  for (int off = 32; off; off >>= 1) s += __shfl_xor(s, off, 64);
  if ((tid & 63) == 0) red[4 + wv] = s;
  __syncthreads();                          // fences all arow reads before P writes
  s = red[4] + red[5] + red[6] + red[7];
  float inv = 1.0f / s;
  if (j0 < jlen) {
    ushort4 u;
    u.x = f2bf(a0.x * inv); u.y = f2bf(a0.y * inv);
    u.z = f2bf(a0.z * inv); u.w = f2bf(a0.w * inv);
    *(ushort4*)(prow + j0) = u;
  }
  if (j1 < jlen) {
    ushort4 u;
    u.x = f2bf(a1.x * inv); u.y = f2bf(a1.y * inv);
    u.z = f2bf(a1.z * inv); u.w = f2bf(a1.w * inv);
    *(ushort4*)(prow + j1) = u;
  }
  if (tid == 0) denom[row] = s;
}

extern "C" void kernel_launch(void* const* d_in, const int* in_sizes, int n_in,
                              void* d_out, int out_size, void* d_ws, size_t ws_size,
                              hipStream_t stream) {
  const float* x    = (const float*)d_in[0];
  const float* W    = (const float*)d_in[1];
  const float* bias = (const float*)d_in[2];

  // ws layout (201,326,592 B):
  //  [0,         67108864)  qk bf16 [8192][4096] (q cols 0..2047, k cols 2048..4095)
  //  [67108864, 100663296)  vT bf16 [4][2048][2048]   (written by gemm<0> epilogue)
  //  [100663296,134217728)  xb bf16 [8192][2048]      (dead after gemm<0>)
  //  [134217728,201326592)  phase1: Wt bf16 (first 25MB, dead after gemm<0>)
  //                         phase2: att fp32 / P bf16 in-place (row stride 4096 u16)
  if (ws_size < 201326592u) return;

  char* w = (char*)d_ws;
  u16*   qk  = (u16*)w;
  u16*   vT  = (u16*)(w + 67108864);
  u16*   xb  = (u16*)(w + 100663296);
  u16*   Wt  = (u16*)(w + 134217728);
  float* att = (float*)(w + 134217728);
  u16*   P   = (u16*)(w + 134217728);

  float* y     = (float*)d_out;
  float* denom = y + (size_t)4 * SEQ * SEQ;

  cast_x_kern<<<16384, 256, 0, stream>>>(x, xb);
  castT_W_kern<<<dim3(96, 32), 256, 0, stream>>>(W, Wt);
  gemm256<0><<<768, 512, 0, stream>>>(xb, Wt, qk, vT, bias);
  gemm256<1><<<144, 512, 0, stream>>>(qk, nullptr, att, nullptr, nullptr);
  softmax_kern<<<8192, 256, 0, stream>>>(att, P, denom);
  gemm256<2><<<256, 512, 0, stream>>>(P, vT, y, nullptr, nullptr);
}